// Round 3
// baseline (642.606 us; speedup 1.0000x reference)
//
#include <hip/hip_runtime.h>
#include <hip/hip_fp16.h>

#define NN 10000
#define FF 32
#define PG 4      // pairs per group
#define NGRP 24   // 96 pairs / PG

__device__ __forceinline__ unsigned short f2h(float f){
  union { unsigned short s; _Float16 h; } c; c.h = (_Float16)f; return c.s;
}

// acc.x += w * lo_f16(h); acc.y += w * hi_f16(h)  -- one VOP3P instr each.
// op_sel_hi[1]=1 marks S1 as f16; op_sel[1] picks the half. S0/S2 stay f32.
__device__ __forceinline__ void fmix2(float& ax, float& ay, float w, unsigned h){
  asm("v_fma_mix_f32 %0, %2, %3, %0 op_sel_hi:[0,1,0]\n\t"
      "v_fma_mix_f32 %1, %2, %3, %1 op_sel:[0,1,0] op_sel_hi:[0,1,0]"
      : "+v"(ax), "+v"(ay) : "v"(w), "v"(h));
}

// ---- CSR build -------------------------------------------------------------
__global__ void k_count(const int* __restrict__ dst, int* __restrict__ cnt, int E){
  int e = blockIdx.x * 256 + threadIdx.x;
  if (e < E) atomicAdd(&cnt[dst[e]], 1);
}

// exclusive scan of PADDED counts (pad to multiple of 4); dinv from real count.
// Also computes W12 = W1@W2 and bb = b1@W2 (fused to save a dispatch).
__global__ __launch_bounds__(1024) void k_scan(const int* __restrict__ cnt,
                                               int* __restrict__ off,
                                               float* __restrict__ dinv,
                                               const float* __restrict__ W1,
                                               const float* __restrict__ W2,
                                               const float* __restrict__ b1,
                                               float* __restrict__ W12,
                                               float* __restrict__ bb){
  __shared__ int wsum[16];
  __shared__ int carry;
  int tid = threadIdx.x, lane = tid & 63, wv = tid >> 6;
  if (tid == 0) carry = 0;
  __syncthreads();
  for (int base = 0; base < NN; base += 1024){
    int i = base + tid;
    int c = (i < NN) ? cnt[i] : 0;
    int v = (c + 3) & ~3;                      // padded degree
    int s = v;
    #pragma unroll
    for (int o = 1; o < 64; o <<= 1){
      int t = __shfl_up(s, o, 64);
      if (lane >= o) s += t;
    }
    if (lane == 63) wsum[wv] = s;
    __syncthreads();
    if (tid == 0){
      int a = carry;
      #pragma unroll
      for (int k = 0; k < 16; ++k){ int t = wsum[k]; wsum[k] = a; a += t; }
      carry = a;
    }
    __syncthreads();
    if (i < NN){
      off[i]  = wsum[wv] + s - v;              // exclusive padded offset
      dinv[i] = rsqrtf((float)(c + 1));        // real degree + self loop
    }
    __syncthreads();
  }
  if (tid == 0) off[NN] = carry;
  // fused W12 / bb
  for (int idx = tid; idx < 33 * 32; idx += 1024){
    int k = idx >> 5, j = idx & 31;
    float s = 0.f;
    for (int m = 0; m < 64; ++m) s += W1[k * 64 + m] * W2[m * 32 + j];
    W12[idx] = s;
  }
  if (tid < 32){
    int j = tid;
    float s = 0.f;
    for (int m = 0; m < 64; ++m) s += b1[m] * W2[m * 32 + j];
    bb[j] = s;
  }
}

// csr entry: {row byte offset (src*256), fp32 weight dinv[src]}
// pad holes (memset 0) read row 0 with weight 0.0 -> harmless.
__global__ void k_scatter(const int* __restrict__ ei, const int* __restrict__ off,
                          int* __restrict__ cur, const float* __restrict__ dinv,
                          int2* __restrict__ csr, int E){
  int e = blockIdx.x * 256 + threadIdx.x;
  if (e >= E) return;
  int s = ei[e], d = ei[E + e];
  int pos = off[d] + atomicAdd(&cur[d], 1);
  csr[pos] = make_int2(s << 8, __float_as_int(dinv[s]));
}

// ---- s[n] = rowsum(A) ------------------------------------------------------
__global__ void k_srow(const int* __restrict__ off, const int2* __restrict__ csr,
                       const float* __restrict__ dinv, float* __restrict__ srow){
  int n = blockIdx.x * 256 + threadIdx.x;
  if (n >= NN) return;
  float a = dinv[n];
  int e0 = off[n], e1 = off[n + 1];
  for (int j = e0; j < e1; ++j) a += __int_as_float(csr[j].y);  // pads add 0
  srow[n] = dinv[n] * a;
}

// ---- GEMM1 v2: one thread = one (pg, node), all 32 features ----------------
__global__ __launch_bounds__(256) void k_gemm1(const float* __restrict__ x,
    const float* __restrict__ mask, const float* __restrict__ W12,
    unsigned* __restrict__ hw){
  const int pg = blockIdx.y;                  // 0..95 (b*24+h)
  const int n  = blockIdx.x * 256 + threadIdx.x;
  const int grp = pg >> 2, p = pg & 3;
  const float mv = mask[pg];
  float acc[32];
  #pragma unroll
  for (int f = 0; f < 32; ++f) acc[f] = mv * W12[32 * 32 + f];  // mask row
  if (n >= NN) return;
  const float4* xp = (const float4*)(x + (size_t)pg * (NN * FF) + (size_t)n * FF);
  float xv[32];
  #pragma unroll
  for (int i = 0; i < 8; ++i){
    float4 v = xp[i];
    xv[4*i]   = v.x; xv[4*i+1] = v.y;
    xv[4*i+2] = v.z; xv[4*i+3] = v.w;
  }
  #pragma unroll
  for (int k = 0; k < 32; ++k){
    const float xk = xv[k];
    #pragma unroll
    for (int f = 0; f < 32; ++f) acc[f] += xk * W12[k * 32 + f];
  }
  unsigned* hwg = hw + (size_t)grp * (NN * 64) + ((size_t)n << 6) + (p << 4);
  #pragma unroll
  for (int j = 0; j < 4; ++j){
    uint4 u;
    u.x = (unsigned)f2h(acc[8*j+0]) | ((unsigned)f2h(acc[8*j+1]) << 16);
    u.y = (unsigned)f2h(acc[8*j+2]) | ((unsigned)f2h(acc[8*j+3]) << 16);
    u.z = (unsigned)f2h(acc[8*j+4]) | ((unsigned)f2h(acc[8*j+5]) << 16);
    u.w = (unsigned)f2h(acc[8*j+6]) | ((unsigned)f2h(acc[8*j+7]) << 16);
    ((uint4*)hwg)[j] = u;
  }
}

// ---- triple edge aggregation: groups {t, t+8, t+16} share one CSR walk -----
// Per edge-quad: 2 csr int4 loads + 4 voffsets serve 12 gathers (3 V bases,
// saddr form) and 24 v_fma_mix into 6 independent accumulator chains.
// 2-deep pipeline: csr quad q+2 loading, 12 gathers of q+1 in flight, fma on q.
__device__ __forceinline__ void agg_edges3(int e0, int e1,
    const int2* __restrict__ csr,
    const char* __restrict__ V0, const char* __restrict__ V1,
    const char* __restrict__ V2, int loff,
    float& ax0, float& ay0, float& ax1, float& ay1, float& ax2, float& ay2){
  int nq = (e1 - e0) >> 2;
  if (nq <= 0) return;
  const int4* c4 = (const int4*)(csr + e0);
  int qlast = nq - 1;
  int4 ca0 = c4[0], cb0 = c4[1];
  int i1 = (1 <= qlast) ? 1 : qlast;
  int4 ca1 = c4[2 * i1], cb1 = c4[2 * i1 + 1];
  unsigned a0 = (unsigned)(ca0.x + loff), a1 = (unsigned)(ca0.z + loff);
  unsigned a2 = (unsigned)(cb0.x + loff), a3 = (unsigned)(cb0.z + loff);
  unsigned r00 = *(const unsigned*)(V0 + a0), r01 = *(const unsigned*)(V0 + a1);
  unsigned r02 = *(const unsigned*)(V0 + a2), r03 = *(const unsigned*)(V0 + a3);
  unsigned r10 = *(const unsigned*)(V1 + a0), r11 = *(const unsigned*)(V1 + a1);
  unsigned r12 = *(const unsigned*)(V1 + a2), r13 = *(const unsigned*)(V1 + a3);
  unsigned r20 = *(const unsigned*)(V2 + a0), r21 = *(const unsigned*)(V2 + a1);
  unsigned r22 = *(const unsigned*)(V2 + a2), r23 = *(const unsigned*)(V2 + a3);
  for (int q = 0; q < nq; ++q){
    unsigned b0 = (unsigned)(ca1.x + loff), b1 = (unsigned)(ca1.z + loff);
    unsigned b2 = (unsigned)(cb1.x + loff), b3 = (unsigned)(cb1.z + loff);
    unsigned s00 = *(const unsigned*)(V0 + b0), s01 = *(const unsigned*)(V0 + b1);
    unsigned s02 = *(const unsigned*)(V0 + b2), s03 = *(const unsigned*)(V0 + b3);
    unsigned s10 = *(const unsigned*)(V1 + b0), s11 = *(const unsigned*)(V1 + b1);
    unsigned s12 = *(const unsigned*)(V1 + b2), s13 = *(const unsigned*)(V1 + b3);
    unsigned s20 = *(const unsigned*)(V2 + b0), s21 = *(const unsigned*)(V2 + b1);
    unsigned s22 = *(const unsigned*)(V2 + b2), s23 = *(const unsigned*)(V2 + b3);
    int i2 = (q + 2 <= qlast) ? q + 2 : qlast;
    int4 na = c4[2 * i2], nb = c4[2 * i2 + 1];
    float w0 = __int_as_float(ca0.y), w1 = __int_as_float(ca0.w);
    float w2 = __int_as_float(cb0.y), w3 = __int_as_float(cb0.w);
    fmix2(ax0, ay0, w0, r00); fmix2(ax0, ay0, w1, r01);
    fmix2(ax0, ay0, w2, r02); fmix2(ax0, ay0, w3, r03);
    fmix2(ax1, ay1, w0, r10); fmix2(ax1, ay1, w1, r11);
    fmix2(ax1, ay1, w2, r12); fmix2(ax1, ay1, w3, r13);
    fmix2(ax2, ay2, w0, r20); fmix2(ax2, ay2, w1, r21);
    fmix2(ax2, ay2, w2, r22); fmix2(ax2, ay2, w3, r23);
    ca0 = ca1; cb0 = cb1; ca1 = na; cb1 = nb;
    r00 = s00; r01 = s01; r02 = s02; r03 = s03;
    r10 = s10; r11 = s11; r12 = s12; r13 = s13;
    r20 = s20; r21 = s21; r22 = s22; r23 = s23;
  }
}

// ---- agg layer 1 (triple): t1 = A*hw for groups {t, t+8, t+16} -------------
// 8 triples <-> 8 XCDs exactly: triple = bx & 7, chunk = bx >> 3. Each XCD's
// L2 holds only its own 3 slices (7.7 MB) for the whole kernel.
__global__ __launch_bounds__(256) void k_agg1(const int* __restrict__ off,
    const int2* __restrict__ csr, const float* __restrict__ dinv,
    const unsigned int* __restrict__ V, unsigned int* __restrict__ T){
  int t3 = blockIdx.x & 7, chunk = blockIdx.x >> 3;
  int tid = threadIdx.x;
  int l = tid & 63;
  int wv = __builtin_amdgcn_readfirstlane(tid) >> 6;   // wave-uniform
  const char* V0 = (const char*)(V + (size_t)(t3     ) * (NN * 64));
  const char* V1 = (const char*)(V + (size_t)(t3 +  8) * (NN * 64));
  const char* V2 = (const char*)(V + (size_t)(t3 + 16) * (NN * 64));
  unsigned int* T0 = T + (size_t)(t3     ) * (NN * 64);
  unsigned int* T1 = T + (size_t)(t3 +  8) * (NN * 64);
  unsigned int* T2 = T + (size_t)(t3 + 16) * (NN * 64);
  int loff = l * 4;
  for (int it = 0; it < 4; ++it){
    int n = chunk * 16 + wv * 4 + it;
    float din = dinv[n];
    int e0 = off[n], e1 = off[n + 1];
    unsigned so = (unsigned)((n << 8) + loff);
    float ax0 = 0.f, ay0 = 0.f, ax1 = 0.f, ay1 = 0.f, ax2 = 0.f, ay2 = 0.f;
    fmix2(ax0, ay0, din, *(const unsigned*)(V0 + so));
    fmix2(ax1, ay1, din, *(const unsigned*)(V1 + so));
    fmix2(ax2, ay2, din, *(const unsigned*)(V2 + so));
    agg_edges3(e0, e1, csr, V0, V1, V2, loff, ax0, ay0, ax1, ay1, ax2, ay2);
    size_t ti = ((size_t)n << 6) + l;
    T0[ti] = (unsigned)f2h(din * ax0) | ((unsigned)f2h(din * ay0) << 16);
    T1[ti] = (unsigned)f2h(din * ax1) | ((unsigned)f2h(din * ay1) << 16);
    T2[ti] = (unsigned)f2h(din * ax2) | ((unsigned)f2h(din * ay2) << 16);
  }
}

// ---- agg layer 2 + epilogue (triple): out = tanh(A*t1 + srow*bb + b2) ------
__global__ __launch_bounds__(256) void k_agg2(const int* __restrict__ off,
    const int2* __restrict__ csr, const float* __restrict__ dinv,
    const float* __restrict__ srow, const float* __restrict__ bb,
    const float* __restrict__ b2, const unsigned int* __restrict__ V,
    float* __restrict__ out){
  int t3 = blockIdx.x & 7, chunk = blockIdx.x >> 3;
  int tid = threadIdx.x;
  int l = tid & 63;
  int wv = __builtin_amdgcn_readfirstlane(tid) >> 6;
  int p = l >> 4, fi = l & 15;
  const char* V0 = (const char*)(V + (size_t)(t3     ) * (NN * 64));
  const char* V1 = (const char*)(V + (size_t)(t3 +  8) * (NN * 64));
  const char* V2 = (const char*)(V + (size_t)(t3 + 16) * (NN * 64));
  float2 bbq = ((const float2*)bb)[fi];
  float2 b2q = ((const float2*)b2)[fi];
  float* out0 = out + (size_t)((t3     ) * PG + p) * (NN * FF);
  float* out1 = out + (size_t)((t3 +  8) * PG + p) * (NN * FF);
  float* out2 = out + (size_t)((t3 + 16) * PG + p) * (NN * FF);
  int loff = l * 4;
  for (int it = 0; it < 4; ++it){
    int n = chunk * 16 + wv * 4 + it;
    float din = dinv[n];
    int e0 = off[n], e1 = off[n + 1];
    unsigned so = (unsigned)((n << 8) + loff);
    float ax0 = 0.f, ay0 = 0.f, ax1 = 0.f, ay1 = 0.f, ax2 = 0.f, ay2 = 0.f;
    fmix2(ax0, ay0, din, *(const unsigned*)(V0 + so));
    fmix2(ax1, ay1, din, *(const unsigned*)(V1 + so));
    fmix2(ax2, ay2, din, *(const unsigned*)(V2 + so));
    agg_edges3(e0, e1, csr, V0, V1, V2, loff, ax0, ay0, ax1, ay1, ax2, ay2);
    float sr = srow[n];
    float bx_ = sr * bbq.x + b2q.x, by_ = sr * bbq.y + b2q.y;
    float2 o0, o1, o2;
    o0.x = tanhf(din * ax0 + bx_); o0.y = tanhf(din * ay0 + by_);
    o1.x = tanhf(din * ax1 + bx_); o1.y = tanhf(din * ay1 + by_);
    o2.x = tanhf(din * ax2 + bx_); o2.y = tanhf(din * ay2 + by_);
    size_t ni = (size_t)n * FF;
    ((float2*)(out0 + ni))[fi] = o0;
    ((float2*)(out1 + ni))[fi] = o1;
    ((float2*)(out2 + ni))[fi] = o2;
  }
}

extern "C" void kernel_launch(void* const* d_in, const int* in_sizes, int n_in,
                              void* d_out, int out_size, void* d_ws, size_t ws_size,
                              hipStream_t stream){
  const float* x    = (const float*)d_in[0];
  const float* mask = (const float*)d_in[1];
  const int*   ei   = (const int*)d_in[2];
  const float* W1   = (const float*)d_in[3];
  const float* b1   = (const float*)d_in[4];
  const float* W2   = (const float*)d_in[5];
  const float* b2   = (const float*)d_in[6];
  float* out = (float*)d_out;
  const int E = in_sizes[2] / 2;   // 320000
  const int CSRCAP = E + 3 * NN + 64;  // padded-to-4 worst case + overread slack

  char* wsp = (char*)d_ws;
  auto alloc = [&](size_t bytes) -> char* {
    char* p = wsp; wsp += (bytes + 255) & ~(size_t)255; return p;
  };
  int*   cnt  = (int*)  alloc((size_t)NN * 4);
  int*   off  = (int*)  alloc((size_t)(NN + 1) * 4);
  int*   cur  = (int*)  alloc((size_t)NN * 4);
  float* dinv = (float*)alloc((size_t)NN * 4);
  float* srow = (float*)alloc((size_t)NN * 4);
  float* W12  = (float*)alloc(33 * 32 * 4);
  float* bbv  = (float*)alloc(32 * 4);
  int2*  csr  = (int2*) alloc((size_t)CSRCAP * 8);
  const size_t per_group = (size_t)NN * 64 * 4;    // [n][4p][32f] fp16 = 2.56MB
  unsigned int* hw = (unsigned int*)alloc((size_t)NGRP * per_group);
  unsigned int* t1 = (unsigned int*)alloc((size_t)NGRP * per_group);

  hipMemsetAsync(cnt, 0, (size_t)NN * 4, stream);
  hipMemsetAsync(cur, 0, (size_t)NN * 4, stream);
  hipMemsetAsync(csr, 0, (size_t)CSRCAP * 8, stream);   // pad entries: row 0, w=0
  k_count  <<<(E + 255) / 256, 256, 0, stream>>>(ei + E, cnt, E);
  k_scan   <<<1, 1024, 0, stream>>>(cnt, off, dinv, W1, W2, b1, W12, bbv);
  k_scatter<<<(E + 255) / 256, 256, 0, stream>>>(ei, off, cur, dinv, csr, E);
  k_srow   <<<(NN + 255) / 256, 256, 0, stream>>>(off, csr, dinv, srow);

  k_gemm1<<<dim3(40, 96), 256, 0, stream>>>(x, mask, W12, hw);
  k_agg1 <<<5000, 256, 0, stream>>>(off, csr, dinv, hw, t1);
  k_agg2 <<<5000, 256, 0, stream>>>(off, csr, dinv, srow, bbv, b2, t1, out);
}

// Round 4
// 549.738 us; speedup vs baseline: 1.1689x; 1.1689x over previous
//
#include <hip/hip_runtime.h>
#include <hip/hip_fp16.h>

#define NN 10000
#define FF 32
#define PG 4      // pairs per group
#define NGRP 24   // 96 pairs / PG

__device__ __forceinline__ unsigned short f2h(float f){
  union { unsigned short s; _Float16 h; } c; c.h = (_Float16)f; return c.s;
}

// acc.x += w * lo_f16(h); acc.y += w * hi_f16(h)  -- one VOP3P instr each.
// op_sel_hi[1]=1 marks S1 as f16; op_sel[1] picks the half. S0/S2 stay f32.
__device__ __forceinline__ void fmix2(float& ax, float& ay, float w, unsigned h){
  asm("v_fma_mix_f32 %0, %2, %3, %0 op_sel_hi:[0,1,0]\n\t"
      "v_fma_mix_f32 %1, %2, %3, %1 op_sel:[0,1,0] op_sel_hi:[0,1,0]"
      : "+v"(ax), "+v"(ay) : "v"(w), "v"(h));
}

// ---- CSR build -------------------------------------------------------------
__global__ void k_count(const int* __restrict__ dst, int* __restrict__ cnt, int E){
  int e = blockIdx.x * 256 + threadIdx.x;
  if (e < E) atomicAdd(&cnt[dst[e]], 1);
}

// exclusive scan of PADDED counts (pad to multiple of 4); dinv from real count.
// Also computes W12 = W1@W2 and bb = b1@W2 (fused to save a dispatch).
__global__ __launch_bounds__(1024) void k_scan(const int* __restrict__ cnt,
                                               int* __restrict__ off,
                                               float* __restrict__ dinv,
                                               const float* __restrict__ W1,
                                               const float* __restrict__ W2,
                                               const float* __restrict__ b1,
                                               float* __restrict__ W12,
                                               float* __restrict__ bb){
  __shared__ int wsum[16];
  __shared__ int carry;
  int tid = threadIdx.x, lane = tid & 63, wv = tid >> 6;
  if (tid == 0) carry = 0;
  __syncthreads();
  for (int base = 0; base < NN; base += 1024){
    int i = base + tid;
    int c = (i < NN) ? cnt[i] : 0;
    int v = (c + 3) & ~3;                      // padded degree
    int s = v;
    #pragma unroll
    for (int o = 1; o < 64; o <<= 1){
      int t = __shfl_up(s, o, 64);
      if (lane >= o) s += t;
    }
    if (lane == 63) wsum[wv] = s;
    __syncthreads();
    if (tid == 0){
      int a = carry;
      #pragma unroll
      for (int k = 0; k < 16; ++k){ int t = wsum[k]; wsum[k] = a; a += t; }
      carry = a;
    }
    __syncthreads();
    if (i < NN){
      off[i]  = wsum[wv] + s - v;              // exclusive padded offset
      dinv[i] = rsqrtf((float)(c + 1));        // real degree + self loop
    }
    __syncthreads();
  }
  if (tid == 0) off[NN] = carry;
  // fused W12 / bb
  for (int idx = tid; idx < 33 * 32; idx += 1024){
    int k = idx >> 5, j = idx & 31;
    float s = 0.f;
    for (int m = 0; m < 64; ++m) s += W1[k * 64 + m] * W2[m * 32 + j];
    W12[idx] = s;
  }
  if (tid < 32){
    int j = tid;
    float s = 0.f;
    for (int m = 0; m < 64; ++m) s += b1[m] * W2[m * 32 + j];
    bb[j] = s;
  }
}

// csr entry: {row byte offset (src*256), fp32 weight dinv[src]}
// pad holes (memset 0) read row 0 with weight 0.0 -> harmless.
__global__ void k_scatter(const int* __restrict__ ei, const int* __restrict__ off,
                          int* __restrict__ cur, const float* __restrict__ dinv,
                          int2* __restrict__ csr, int E){
  int e = blockIdx.x * 256 + threadIdx.x;
  if (e >= E) return;
  int s = ei[e], d = ei[E + e];
  int pos = off[d] + atomicAdd(&cur[d], 1);
  csr[pos] = make_int2(s << 8, __float_as_int(dinv[s]));
}

// ---- s[n] = rowsum(A) ------------------------------------------------------
__global__ void k_srow(const int* __restrict__ off, const int2* __restrict__ csr,
                       const float* __restrict__ dinv, float* __restrict__ srow){
  int n = blockIdx.x * 256 + threadIdx.x;
  if (n >= NN) return;
  float a = dinv[n];
  int e0 = off[n], e1 = off[n + 1];
  for (int j = e0; j < e1; ++j) a += __int_as_float(csr[j].y);  // pads add 0
  srow[n] = dinv[n] * a;
}

// ---- GEMM1 v2: one thread = one (pg, node), all 32 features ----------------
__global__ __launch_bounds__(256) void k_gemm1(const float* __restrict__ x,
    const float* __restrict__ mask, const float* __restrict__ W12,
    unsigned* __restrict__ hw){
  const int pg = blockIdx.y;                  // 0..95 (b*24+h)
  const int n  = blockIdx.x * 256 + threadIdx.x;
  const int grp = pg >> 2, p = pg & 3;
  const float mv = mask[pg];
  float acc[32];
  #pragma unroll
  for (int f = 0; f < 32; ++f) acc[f] = mv * W12[32 * 32 + f];  // mask row
  if (n >= NN) return;
  const float4* xp = (const float4*)(x + (size_t)pg * (NN * FF) + (size_t)n * FF);
  float xv[32];
  #pragma unroll
  for (int i = 0; i < 8; ++i){
    float4 v = xp[i];
    xv[4*i]   = v.x; xv[4*i+1] = v.y;
    xv[4*i+2] = v.z; xv[4*i+3] = v.w;
  }
  #pragma unroll
  for (int k = 0; k < 32; ++k){
    const float xk = xv[k];
    #pragma unroll
    for (int f = 0; f < 32; ++f) acc[f] += xk * W12[k * 32 + f];
  }
  unsigned* hwg = hw + (size_t)grp * (NN * 64) + ((size_t)n << 6) + (p << 4);
  #pragma unroll
  for (int j = 0; j < 4; ++j){
    uint4 u;
    u.x = (unsigned)f2h(acc[8*j+0]) | ((unsigned)f2h(acc[8*j+1]) << 16);
    u.y = (unsigned)f2h(acc[8*j+2]) | ((unsigned)f2h(acc[8*j+3]) << 16);
    u.z = (unsigned)f2h(acc[8*j+4]) | ((unsigned)f2h(acc[8*j+5]) << 16);
    u.w = (unsigned)f2h(acc[8*j+6]) | ((unsigned)f2h(acc[8*j+7]) << 16);
    ((uint4*)hwg)[j] = u;
  }
}

// ---- block->group mapping: pin each group to one XCD (blockIdx%8) ----------
// One group slice (2.56 MB) per XCD at a time -> gathers stay L2-resident.
__device__ __forceinline__ void map_block(int bx, int& grp, int& chunk){
  int r  = bx / 5000;       // 0..2
  int w8 = bx % 5000;
  grp   = r * 8 + (w8 & 7);
  chunk = w8 >> 3;          // 0..624
}

// ---- 4-deep pipelined edge accumulation ------------------------------------
// 4 role-fixed buffers (A..D): gathers lead compute by 4 quads (~160+ cyc of
// covered L2 latency, 16 loads in flight/wave), scalar csr leads by 8.
// No VGPR rotation movs: fma_mix consumes a buffer, gathers refill it.
// All control (n, e0, e1, nq) is wave-uniform -> tail branches are s_cbranch.
// Clamped prefetch indices dup qlast (L1-hot); each quad computed exactly once.
__device__ __forceinline__ void agg_edges(int e0, int e1,
    const int2* __restrict__ csr, const char* __restrict__ Vb, int loff,
    float& ax, float& ay){
  int nq = (e1 - e0) >> 2;
  if (nq <= 0) return;
  const int4* c4 = (const int4*)(csr + e0);
  const int qlast = nq - 1;
  int4 cA, dA, cB, dB, cC, dC, cD, dD;          // csr for quad resident in r*
  int4 cA2, dA2, cB2, dB2, cC2, dC2, cD2, dD2;  // csr for quad+4 (gather issue)
  unsigned rA0,rA1,rA2,rA3, rB0,rB1,rB2,rB3;
  unsigned rC0,rC1,rC2,rC3, rD0,rD1,rD2,rD3;
  {
    int i1 = 1<=qlast?1:qlast, i2 = 2<=qlast?2:qlast, i3 = 3<=qlast?3:qlast;
    cA = c4[0];      dA = c4[1];
    cB = c4[2*i1];   dB = c4[2*i1+1];
    cC = c4[2*i2];   dC = c4[2*i2+1];
    cD = c4[2*i3];   dD = c4[2*i3+1];
    int i4 = 4<=qlast?4:qlast, i5 = 5<=qlast?5:qlast;
    int i6 = 6<=qlast?6:qlast, i7 = 7<=qlast?7:qlast;
    cA2 = c4[2*i4];  dA2 = c4[2*i4+1];
    cB2 = c4[2*i5];  dB2 = c4[2*i5+1];
    cC2 = c4[2*i6];  dC2 = c4[2*i6+1];
    cD2 = c4[2*i7];  dD2 = c4[2*i7+1];
    rA0 = *(const unsigned*)(Vb + (unsigned)(cA.x + loff));
    rA1 = *(const unsigned*)(Vb + (unsigned)(cA.z + loff));
    rA2 = *(const unsigned*)(Vb + (unsigned)(dA.x + loff));
    rA3 = *(const unsigned*)(Vb + (unsigned)(dA.z + loff));
    rB0 = *(const unsigned*)(Vb + (unsigned)(cB.x + loff));
    rB1 = *(const unsigned*)(Vb + (unsigned)(cB.z + loff));
    rB2 = *(const unsigned*)(Vb + (unsigned)(dB.x + loff));
    rB3 = *(const unsigned*)(Vb + (unsigned)(dB.z + loff));
    rC0 = *(const unsigned*)(Vb + (unsigned)(cC.x + loff));
    rC1 = *(const unsigned*)(Vb + (unsigned)(cC.z + loff));
    rC2 = *(const unsigned*)(Vb + (unsigned)(dC.x + loff));
    rC3 = *(const unsigned*)(Vb + (unsigned)(dC.z + loff));
    rD0 = *(const unsigned*)(Vb + (unsigned)(cD.x + loff));
    rD1 = *(const unsigned*)(Vb + (unsigned)(cD.z + loff));
    rD2 = *(const unsigned*)(Vb + (unsigned)(dD.x + loff));
    rD3 = *(const unsigned*)(Vb + (unsigned)(dD.z + loff));
  }
  int q = 0;
  #define AGG_STEP(cX, dX, cX2, dX2, r0, r1, r2, r3, LEAD)              \
    do {                                                                \
      fmix2(ax, ay, __int_as_float(cX.y), r0);                          \
      fmix2(ax, ay, __int_as_float(cX.w), r1);                          \
      fmix2(ax, ay, __int_as_float(dX.y), r2);                          \
      fmix2(ax, ay, __int_as_float(dX.w), r3);                          \
      r0 = *(const unsigned*)(Vb + (unsigned)(cX2.x + loff));           \
      r1 = *(const unsigned*)(Vb + (unsigned)(cX2.z + loff));           \
      r2 = *(const unsigned*)(Vb + (unsigned)(dX2.x + loff));           \
      r3 = *(const unsigned*)(Vb + (unsigned)(dX2.z + loff));           \
      cX = cX2; dX = dX2;                                               \
      int ii = q + (LEAD); ii = ii <= qlast ? ii : qlast;               \
      cX2 = c4[2*ii]; dX2 = c4[2*ii+1];                                 \
    } while (0)
  for (; q + 3 < nq; q += 4){
    AGG_STEP(cA,dA,cA2,dA2, rA0,rA1,rA2,rA3, 8);
    AGG_STEP(cB,dB,cB2,dB2, rB0,rB1,rB2,rB3, 9);
    AGG_STEP(cC,dC,cC2,dC2, rC0,rC1,rC2,rC3, 10);
    AGG_STEP(cD,dD,cD2,dD2, rD0,rD1,rD2,rD3, 11);
  }
  #undef AGG_STEP
  int rem = nq - q;   // 0..3 (wave-uniform)
  if (rem > 0){
    fmix2(ax, ay, __int_as_float(cA.y), rA0);
    fmix2(ax, ay, __int_as_float(cA.w), rA1);
    fmix2(ax, ay, __int_as_float(dA.y), rA2);
    fmix2(ax, ay, __int_as_float(dA.w), rA3);
  }
  if (rem > 1){
    fmix2(ax, ay, __int_as_float(cB.y), rB0);
    fmix2(ax, ay, __int_as_float(cB.w), rB1);
    fmix2(ax, ay, __int_as_float(dB.y), rB2);
    fmix2(ax, ay, __int_as_float(dB.w), rB3);
  }
  if (rem > 2){
    fmix2(ax, ay, __int_as_float(cC.y), rC0);
    fmix2(ax, ay, __int_as_float(cC.w), rC1);
    fmix2(ax, ay, __int_as_float(dC.y), rC2);
    fmix2(ax, ay, __int_as_float(dC.w), rC3);
  }
}

// ---- agg layer 1: t1 = A*hw (fp16 rows, fp32 accum) ------------------------
__global__ __launch_bounds__(256) void k_agg1(const int* __restrict__ off,
    const int2* __restrict__ csr, const float* __restrict__ dinv,
    const unsigned int* __restrict__ V, unsigned int* __restrict__ T){
  int grp, chunk; map_block(blockIdx.x, grp, chunk);
  int tid = threadIdx.x;
  int l = tid & 63;
  int wv = __builtin_amdgcn_readfirstlane(tid) >> 6;   // wave-uniform
  const char* Vb = (const char*)(V + (size_t)grp * (NN * 64));
  unsigned int* Tg = T + (size_t)grp * (NN * 64);
  int loff = l * 4;
  for (int it = 0; it < 4; ++it){
    int n = chunk * 16 + wv * 4 + it;
    float din = dinv[n];
    int e0 = off[n], e1 = off[n + 1];
    unsigned sv = *(const unsigned*)(Vb + (unsigned)((n << 8) + loff));
    float ax = 0.f, ay = 0.f;
    fmix2(ax, ay, din, sv);
    agg_edges(e0, e1, csr, Vb, loff, ax, ay);
    Tg[((size_t)n << 6) + l] =
        (unsigned)f2h(din * ax) | ((unsigned)f2h(din * ay) << 16);
  }
}

// ---- agg layer 2 + epilogue: out = tanh(A*t1 + srow*bb + b2) fp32 ----------
__global__ __launch_bounds__(256) void k_agg2(const int* __restrict__ off,
    const int2* __restrict__ csr, const float* __restrict__ dinv,
    const float* __restrict__ srow, const float* __restrict__ bb,
    const float* __restrict__ b2, const unsigned int* __restrict__ V,
    float* __restrict__ out){
  int grp, chunk; map_block(blockIdx.x, grp, chunk);
  int tid = threadIdx.x;
  int l = tid & 63;
  int wv = __builtin_amdgcn_readfirstlane(tid) >> 6;
  int p = l >> 4, fi = l & 15;
  const char* Vb = (const char*)(V + (size_t)grp * (NN * 64));
  int pg = grp * PG + p;
  float2 bbq = ((const float2*)bb)[fi];
  float2 b2q = ((const float2*)b2)[fi];
  float* outp = out + (size_t)pg * (NN * FF);
  int loff = l * 4;
  for (int it = 0; it < 4; ++it){
    int n = chunk * 16 + wv * 4 + it;
    float din = dinv[n];
    int e0 = off[n], e1 = off[n + 1];
    unsigned sv = *(const unsigned*)(Vb + (unsigned)((n << 8) + loff));
    float ax = 0.f, ay = 0.f;
    fmix2(ax, ay, din, sv);
    agg_edges(e0, e1, csr, Vb, loff, ax, ay);
    float sr = srow[n];
    float2 o;
    o.x = tanhf(din * ax + sr * bbq.x + b2q.x);
    o.y = tanhf(din * ay + sr * bbq.y + b2q.y);
    ((float2*)(outp + (size_t)n * FF))[fi] = o;
  }
}

extern "C" void kernel_launch(void* const* d_in, const int* in_sizes, int n_in,
                              void* d_out, int out_size, void* d_ws, size_t ws_size,
                              hipStream_t stream){
  const float* x    = (const float*)d_in[0];
  const float* mask = (const float*)d_in[1];
  const int*   ei   = (const int*)d_in[2];
  const float* W1   = (const float*)d_in[3];
  const float* b1   = (const float*)d_in[4];
  const float* W2   = (const float*)d_in[5];
  const float* b2   = (const float*)d_in[6];
  float* out = (float*)d_out;
  const int E = in_sizes[2] / 2;   // 320000
  const int CSRCAP = E + 3 * NN + 64;  // padded-to-4 worst case + overread slack

  char* wsp = (char*)d_ws;
  auto alloc = [&](size_t bytes) -> char* {
    char* p = wsp; wsp += (bytes + 255) & ~(size_t)255; return p;
  };
  int*   cnt  = (int*)  alloc((size_t)NN * 4);
  int*   off  = (int*)  alloc((size_t)(NN + 1) * 4);
  int*   cur  = (int*)  alloc((size_t)NN * 4);
  float* dinv = (float*)alloc((size_t)NN * 4);
  float* srow = (float*)alloc((size_t)NN * 4);
  float* W12  = (float*)alloc(33 * 32 * 4);
  float* bbv  = (float*)alloc(32 * 4);
  int2*  csr  = (int2*) alloc((size_t)CSRCAP * 8);
  const size_t per_group = (size_t)NN * 64 * 4;    // [n][4p][32f] fp16 = 2.56MB
  unsigned int* hw = (unsigned int*)alloc((size_t)NGRP * per_group);
  unsigned int* t1 = (unsigned int*)alloc((size_t)NGRP * per_group);

  hipMemsetAsync(cnt, 0, (size_t)NN * 4, stream);
  hipMemsetAsync(cur, 0, (size_t)NN * 4, stream);
  hipMemsetAsync(csr, 0, (size_t)CSRCAP * 8, stream);   // pad entries: row 0, w=0
  k_count  <<<(E + 255) / 256, 256, 0, stream>>>(ei + E, cnt, E);
  k_scan   <<<1, 1024, 0, stream>>>(cnt, off, dinv, W1, W2, b1, W12, bbv);
  k_scatter<<<(E + 255) / 256, 256, 0, stream>>>(ei, off, cur, dinv, csr, E);
  k_srow   <<<(NN + 255) / 256, 256, 0, stream>>>(off, csr, dinv, srow);

  k_gemm1<<<dim3(40, 96), 256, 0, stream>>>(x, mask, W12, hw);
  k_agg1 <<<15000, 256, 0, stream>>>(off, csr, dinv, hw, t1);
  k_agg2 <<<15000, 256, 0, stream>>>(off, csr, dinv, srow, bbv, b2, t1, out);
}